// Round 6
// baseline (91.327 us; speedup 1.0000x reference)
//
#include <hip/hip_runtime.h>
#include <hip/hip_bf16.h>
#include <math.h>

#define NB     2048
#define NC     1000
#define DDIM   128
#define LDT    136      // LDS row stride in bf16 (+8 pad)
#define NCARR  136u     // proto carrier blocks (triangular by<=bx, bx<16)

typedef __attribute__((ext_vector_type(8))) short  short8;
typedef __attribute__((ext_vector_type(4))) float  floatx4;

__device__ __forceinline__ float bf2f(unsigned short b) {
    union { float f; unsigned int u; } v; v.u = ((unsigned int)b) << 16;
    return v.f;
}

// stage 64 rows x 128 k of fp32 -> bf16 LDS tile (RNE), coalesced float4 reads
__device__ __forceinline__ void stage_cvt(const float* __restrict__ src, int row0, int clampr,
                                          unsigned short* __restrict__ lds, int t) {
    #pragma unroll
    for (int i = 0; i < 8; ++i) {
        int c = (i * 256 + t) * 4;             // 0..8191
        int r = c >> 7, k = c & 127;
        int gr = row0 + r; if (gr > clampr) gr = clampr;
        float4 v = *(const float4*)(src + gr * DDIM + k);
        union { __hip_bfloat162 h; unsigned int u; } p0, p1;
        p0.h = __float22bfloat162_rn(make_float2(v.x, v.y));
        p1.h = __float22bfloat162_rn(make_float2(v.z, v.w));
        uint2 st; st.x = p0.u; st.y = p1.u;
        *(uint2*)(lds + r * LDT + k) = st;
    }
}

// per-row squared norms of the ROUNDED bf16 values; 4 lanes per row
__device__ __forceinline__ void norm64(const unsigned short* __restrict__ tile,
                                       float* __restrict__ nrm, int t) {
    int r = t >> 2, seg = t & 3;
    const unsigned short* p = tile + r * LDT + seg * 32;
    float q = 0.0f;
    #pragma unroll
    for (int j = 0; j < 4; ++j) {
        short8 v = *(const short8*)(p + j * 8);
        #pragma unroll
        for (int e = 0; e < 8; ++e) { float f = bf2f((unsigned short)v[e]); q = fmaf(f, f, q); }
    }
    q += __shfl_xor(q, 1);
    q += __shfl_xor(q, 2);
    if (seg == 0) nrm[r] = q;
}

// 64x64 block tile: 4 waves, each a 2x2 of 16x16x32 bf16 MFMA tiles
__device__ __forceinline__ void gemm64(const unsigned short* __restrict__ As,
                                       const unsigned short* __restrict__ Bs,
                                       int lane, int w, floatx4 acc[2][2]) {
    int wm = (w >> 1) * 32, wn = (w & 1) * 32;
    int lm = lane & 15, q = lane >> 4;
    #pragma unroll
    for (int ks = 0; ks < 4; ++ks) {
        int ko = ks * 32 + q * 8;
        short8 a0 = *(const short8*)(As + (wm + lm) * LDT + ko);
        short8 a1 = *(const short8*)(As + (wm + 16 + lm) * LDT + ko);
        short8 b0 = *(const short8*)(Bs + (wn + lm) * LDT + ko);
        short8 b1 = *(const short8*)(Bs + (wn + 16 + lm) * LDT + ko);
        acc[0][0] = __builtin_amdgcn_mfma_f32_16x16x32_bf16(a0, b0, acc[0][0], 0, 0, 0);
        acc[0][1] = __builtin_amdgcn_mfma_f32_16x16x32_bf16(a0, b1, acc[0][1], 0, 0, 0);
        acc[1][0] = __builtin_amdgcn_mfma_f32_16x16x32_bf16(a1, b0, acc[1][0], 0, 0, 0);
        acc[1][1] = __builtin_amdgcn_mfma_f32_16x16x32_bf16(a1, b1, acc[1][1], 0, 0, 0);
    }
}

// One launch. Block (by,bx), by=bid>>4 in [0,32), bx=bid&15.
//   by<=bx (136 blocks): proto tile (W[by] x W[bx]) first, reusing Bs for the
//   dist pass; partial -> atomicAdd ws[0], release-increment cnt.
//   All blocks: dist tile (F[by] x W[bx]) -> regs, then relaxed-poll cnt==136,
//   one acquire fence, store proto - dist.
__global__ __launch_bounds__(256) void fused_kernel(const float* __restrict__ F,
                                                    const float* __restrict__ W,
                                                    float* __restrict__ ws,
                                                    float* __restrict__ out) {
    __shared__ __align__(16) unsigned short As[64 * LDT];
    __shared__ __align__(16) unsigned short Bs[64 * LDT];
    __shared__ float nA[64], nB[64], red[4], sproto;
    unsigned int* cnt = (unsigned int*)ws + 1;

    int t = threadIdx.x, bid = blockIdx.x;
    int by = bid >> 4, bx = bid & 15;
    int row0 = by * 64, col0 = bx * 64;
    bool carrier = (by <= bx);            // block-uniform

    int lane = t & 63, w = t >> 6;
    int wm = (w >> 1) * 32, wn = (w & 1) * 32;
    int lm = lane & 15, q = lane >> 4;

    // ---- stage: Bs = W col tile (both passes); As = W row tile (carrier) or F
    stage_cvt(W, col0, NC - 1, Bs, t);
    if (carrier) stage_cvt(W, row0, NC - 1, As, t);
    else         stage_cvt(F, row0, NB - 1, As, t);
    __syncthreads();                                   // S1
    norm64(Bs, nB, t);
    norm64(As, nA, t);
    {
        floatx4 acc[2][2] = {{{0,0,0,0},{0,0,0,0}},{{0,0,0,0},{0,0,0,0}}};
        gemm64(As, Bs, lane, w, acc);
        __syncthreads();                               // S2: norms visible, LDS reads done

        if (carrier) {
            // ---- proto epilogue ----
            float local = 0.0f;
            #pragma unroll
            for (int ti = 0; ti < 2; ++ti)
                #pragma unroll
                for (int tj = 0; tj < 2; ++tj) {
                    int lc2 = wn + tj * 16 + lm;
                    if (col0 + lc2 < NC) {
                        float n2 = nB[lc2];
                        #pragma unroll
                        for (int r = 0; r < 4; ++r) {
                            int lc1 = wm + ti * 16 + q * 4 + r;
                            if (row0 + lc1 < NC) {
                                float d2 = nA[lc1] + n2 - 2.0f * acc[ti][tj][r];
                                local += sqrtf(fmaxf(d2, 0.0f));
                            }
                        }
                    }
                }
            if (by != bx) local *= 2.0f;               // symmetric double-count
            #pragma unroll
            for (int off = 32; off > 0; off >>= 1) local += __shfl_down(local, off);
            if (lane == 0) red[w] = local;
            __syncthreads();                           // S3: red visible, nA reads done
            if (t == 0) {
                atomicAdd(ws, red[0] + red[1] + red[2] + red[3]);  // device scope
                __hip_atomic_fetch_add(cnt, 1u, __ATOMIC_RELEASE, __HIP_MEMORY_SCOPE_AGENT);
            }
            // ---- restage As with F rows for the dist pass (Bs, nB reused) ----
            stage_cvt(F, row0, NB - 1, As, t);
            __syncthreads();                           // S4
            norm64(As, nA, t);
        }
    }

    // ---- dist pass ----
    floatx4 acc[2][2] = {{{0,0,0,0},{0,0,0,0}},{{0,0,0,0},{0,0,0,0}}};
    if (carrier) {
        gemm64(As, Bs, lane, w, acc);
        __syncthreads();                               // S5: nA visible
    } else {
        // non-carrier: acc from pass above was the dist GEMM already — recompute
        // NOT needed; reuse via shared path is messy, so just redo epilogue path:
        gemm64(As, Bs, lane, w, acc);
        __syncthreads();
    }

    float s[2][2][4];
    #pragma unroll
    for (int ti = 0; ti < 2; ++ti)
        #pragma unroll
        for (int tj = 0; tj < 2; ++tj) {
            float n2 = nB[wn + tj * 16 + lm];
            #pragma unroll
            for (int r = 0; r < 4; ++r) {
                float d2 = nA[wm + ti * 16 + q * 4 + r] + n2 - 2.0f * acc[ti][tj][r];
                s[ti][tj][r] = sqrtf(fmaxf(d2, 0.0f));
            }
        }

    // ---- wait for proto sum: relaxed system-scope poll (no cache invalidates),
    //      one acquire fence on exit ----
    if (t == 0) {
        while (__hip_atomic_load(cnt, __ATOMIC_RELAXED, __HIP_MEMORY_SCOPE_SYSTEM) != NCARR)
            __builtin_amdgcn_s_sleep(32);
        __builtin_amdgcn_fence(__ATOMIC_ACQUIRE, "agent");
        sproto = __hip_atomic_load(ws, __ATOMIC_RELAXED, __HIP_MEMORY_SCOPE_SYSTEM);
    }
    __syncthreads();
    float proto = sproto;

    #pragma unroll
    for (int ti = 0; ti < 2; ++ti)
        #pragma unroll
        for (int tj = 0; tj < 2; ++tj) {
            int cg = col0 + wn + tj * 16 + lm;
            if (cg < NC) {
                #pragma unroll
                for (int r = 0; r < 4; ++r) {
                    int mg = row0 + wm + ti * 16 + q * 4 + r;
                    out[mg * NC + cg] = proto - s[ti][tj][r];
                }
            }
        }
}

extern "C" void kernel_launch(void* const* d_in, const int* in_sizes, int n_in,
                              void* d_out, int out_size, void* d_ws, size_t ws_size,
                              hipStream_t stream) {
    const float* F  = (const float*)d_in[0];   // (2048,128)
    const float* Wm = (const float*)d_in[1];   // (1000,128)
    float* out = (float*)d_out;                // (2048,1000)
    float* ws  = (float*)d_ws;

    hipMemsetAsync(ws, 0, 8, stream);          // ws[0]=proto sum, ws[1]=arrive counter
    fused_kernel<<<512, 256, 0, stream>>>(F, Wm, ws, out);
}

// Round 7
// 72.401 us; speedup vs baseline: 1.2614x; 1.2614x over previous
//
#include <hip/hip_runtime.h>
#include <hip/hip_bf16.h>
#include <math.h>

#define NB   2048
#define NC   1000
#define DDIM 128
#define LDT  136      // LDS row stride in bf16 (+8 pad; 272 B rows keep 16B align)
#define NPB  136      // compact triangular proto blocks (by<=bx<16)

typedef __attribute__((ext_vector_type(8))) short  short8;
typedef __attribute__((ext_vector_type(4))) float  floatx4;

__device__ __forceinline__ float bf2f(unsigned short b) {
    union { float f; unsigned int u; } v; v.u = ((unsigned int)b) << 16;
    return v.f;
}

// stage NR rows x 128 k of fp32 -> bf16 LDS tile (RNE), coalesced float4 reads
template <int NR>
__device__ __forceinline__ void stage_cvt(const float* __restrict__ src, int row0, int clampr,
                                          unsigned short* __restrict__ lds, int t) {
    #pragma unroll
    for (int i = 0; i < NR / 2; ++i) {         // NR*128 elems / (256 thr * 4)
        int c = (i * 256 + t) * 4;
        int r = c >> 7, k = c & 127;
        int gr = row0 + r; if (gr > clampr) gr = clampr;
        float4 v = *(const float4*)(src + gr * DDIM + k);
        union { __hip_bfloat162 h; unsigned int u; } p0, p1;
        p0.h = __float22bfloat162_rn(make_float2(v.x, v.y));
        p1.h = __float22bfloat162_rn(make_float2(v.z, v.w));
        uint2 st; st.x = p0.u; st.y = p1.u;
        *(uint2*)(lds + r * LDT + k) = st;
    }
}

// per-row squared norms of the ROUNDED bf16 values; LPR lanes per row
template <int NR>
__device__ __forceinline__ void normrows(const unsigned short* __restrict__ tile,
                                         float* __restrict__ nrm, int t) {
    const int LPR = 256 / NR;                  // lanes per row (4 for 64, 2 for 128)
    const int EPL = DDIM / LPR;                // elems per lane
    int r = t / LPR, seg = t % LPR;
    const unsigned short* p = tile + r * LDT + seg * EPL;
    float q = 0.0f;
    #pragma unroll
    for (int j = 0; j < EPL / 8; ++j) {
        short8 v = *(const short8*)(p + j * 8);
        #pragma unroll
        for (int e = 0; e < 8; ++e) { float f = bf2f((unsigned short)v[e]); q = fmaf(f, f, q); }
    }
    #pragma unroll
    for (int m = 1; m < LPR; m <<= 1) q += __shfl_xor(q, m);
    if (seg == 0) nrm[r] = q;
}

// ---- proto: compact upper-triangle 64x64 tiles, partial -> ws[bid] ---------------
__global__ __launch_bounds__(256) void proto_kernel(const float* __restrict__ W,
                                                    float* __restrict__ ws) {
    __shared__ __align__(16) unsigned short As[64 * LDT];
    __shared__ __align__(16) unsigned short Bs[64 * LDT];
    __shared__ float nA[64], nB[64], red[4];
    int bid = blockIdx.x;
    int by = 0, base = 0;                      // map bid -> (by<=bx<16), uniform loop
    while (base + (16 - by) <= bid) { base += 16 - by; ++by; }
    int bx = by + (bid - base);
    int t = threadIdx.x;
    int row0 = by * 64, col0 = bx * 64;
    stage_cvt<64>(W, row0, NC - 1, As, t);
    stage_cvt<64>(W, col0, NC - 1, Bs, t);
    __syncthreads();
    normrows<64>(As, nA, t);
    normrows<64>(Bs, nB, t);
    int lane = t & 63, w = t >> 6;
    int wm = (w >> 1) * 32, wn = (w & 1) * 32;
    int lm = lane & 15, q = lane >> 4;
    floatx4 acc[2][2] = {{{0,0,0,0},{0,0,0,0}},{{0,0,0,0},{0,0,0,0}}};
    #pragma unroll
    for (int ks = 0; ks < 4; ++ks) {
        int ko = ks * 32 + q * 8;
        short8 a0 = *(const short8*)(As + (wm + lm) * LDT + ko);
        short8 a1 = *(const short8*)(As + (wm + 16 + lm) * LDT + ko);
        short8 b0 = *(const short8*)(Bs + (wn + lm) * LDT + ko);
        short8 b1 = *(const short8*)(Bs + (wn + 16 + lm) * LDT + ko);
        acc[0][0] = __builtin_amdgcn_mfma_f32_16x16x32_bf16(a0, b0, acc[0][0], 0, 0, 0);
        acc[0][1] = __builtin_amdgcn_mfma_f32_16x16x32_bf16(a0, b1, acc[0][1], 0, 0, 0);
        acc[1][0] = __builtin_amdgcn_mfma_f32_16x16x32_bf16(a1, b0, acc[1][0], 0, 0, 0);
        acc[1][1] = __builtin_amdgcn_mfma_f32_16x16x32_bf16(a1, b1, acc[1][1], 0, 0, 0);
    }
    __syncthreads();                           // norms visible
    float local = 0.0f;
    #pragma unroll
    for (int ti = 0; ti < 2; ++ti)
        #pragma unroll
        for (int tj = 0; tj < 2; ++tj) {
            int lc2 = wn + tj * 16 + lm;
            if (col0 + lc2 < NC) {
                float n2 = nB[lc2];
                #pragma unroll
                for (int r = 0; r < 4; ++r) {
                    int lc1 = wm + ti * 16 + q * 4 + r;
                    if (row0 + lc1 < NC) {
                        float d2 = nA[lc1] + n2 - 2.0f * acc[ti][tj][r];
                        local += sqrtf(fmaxf(d2, 0.0f));
                    }
                }
            }
        }
    if (by != bx) local *= 2.0f;               // symmetric double-count
    #pragma unroll
    for (int off = 32; off > 0; off >>= 1) local += __shfl_down(local, off);
    if (lane == 0) red[w] = local;
    __syncthreads();
    if (t == 0) ws[bid] = red[0] + red[1] + red[2] + red[3];
}

// ---- dist: 128x64 tiles, out[b,c] = protoSum - ||f_b - w_c|| ---------------------
__global__ __launch_bounds__(256) void dist_kernel(const float* __restrict__ F,
                                                   const float* __restrict__ W,
                                                   const float* __restrict__ ws,
                                                   float* __restrict__ out) {
    __shared__ __align__(16) unsigned short As[128 * LDT];
    __shared__ __align__(16) unsigned short Bs[64 * LDT];
    __shared__ float nA[128], nB[64], red2[4];
    int t = threadIdx.x;
    int row0 = blockIdx.y * 128, col0 = blockIdx.x * 64;

    float pv = (t < NPB) ? ws[t] : 0.0f;       // proto partials (coalesced)
    stage_cvt<128>(F, row0, NB - 1, As, t);
    stage_cvt<64> (W, col0, NC - 1, Bs, t);
    #pragma unroll
    for (int off = 32; off > 0; off >>= 1) pv += __shfl_down(pv, off);
    if ((t & 63) == 0) red2[t >> 6] = pv;
    __syncthreads();                           // staging + red2 visible
    float proto = red2[0] + red2[1] + red2[2] + red2[3];

    normrows<128>(As, nA, t);
    normrows<64> (Bs, nB, t);
    int lane = t & 63, w = t >> 6;
    int wm = w * 32;                           // wave covers rows [wm, wm+32)
    int lm = lane & 15, q = lane >> 4;
    floatx4 acc[2][4] = {{{0,0,0,0},{0,0,0,0},{0,0,0,0},{0,0,0,0}},
                         {{0,0,0,0},{0,0,0,0},{0,0,0,0},{0,0,0,0}}};
    #pragma unroll
    for (int ks = 0; ks < 4; ++ks) {
        int ko = ks * 32 + q * 8;
        short8 a0 = *(const short8*)(As + (wm + lm) * LDT + ko);
        short8 a1 = *(const short8*)(As + (wm + 16 + lm) * LDT + ko);
        short8 b0 = *(const short8*)(Bs + (lm      ) * LDT + ko);
        short8 b1 = *(const short8*)(Bs + (16 + lm ) * LDT + ko);
        short8 b2 = *(const short8*)(Bs + (32 + lm ) * LDT + ko);
        short8 b3 = *(const short8*)(Bs + (48 + lm ) * LDT + ko);
        acc[0][0] = __builtin_amdgcn_mfma_f32_16x16x32_bf16(a0, b0, acc[0][0], 0, 0, 0);
        acc[0][1] = __builtin_amdgcn_mfma_f32_16x16x32_bf16(a0, b1, acc[0][1], 0, 0, 0);
        acc[0][2] = __builtin_amdgcn_mfma_f32_16x16x32_bf16(a0, b2, acc[0][2], 0, 0, 0);
        acc[0][3] = __builtin_amdgcn_mfma_f32_16x16x32_bf16(a0, b3, acc[0][3], 0, 0, 0);
        acc[1][0] = __builtin_amdgcn_mfma_f32_16x16x32_bf16(a1, b0, acc[1][0], 0, 0, 0);
        acc[1][1] = __builtin_amdgcn_mfma_f32_16x16x32_bf16(a1, b1, acc[1][1], 0, 0, 0);
        acc[1][2] = __builtin_amdgcn_mfma_f32_16x16x32_bf16(a1, b2, acc[1][2], 0, 0, 0);
        acc[1][3] = __builtin_amdgcn_mfma_f32_16x16x32_bf16(a1, b3, acc[1][3], 0, 0, 0);
    }
    __syncthreads();                           // norms visible
    #pragma unroll
    for (int ti = 0; ti < 2; ++ti) {
        #pragma unroll
        for (int c = 0; c < 4; ++c) {
            int lc2 = c * 16 + lm;
            int cg  = col0 + lc2;
            if (cg < NC) {
                float n2 = nB[lc2];
                #pragma unroll
                for (int r = 0; r < 4; ++r) {
                    int lr = wm + ti * 16 + q * 4 + r;
                    int mg = row0 + lr;
                    float d2 = nA[lr] + n2 - 2.0f * acc[ti][c][r];
                    out[mg * NC + cg] = proto - sqrtf(fmaxf(d2, 0.0f));
                }
            }
        }
    }
}

extern "C" void kernel_launch(void* const* d_in, const int* in_sizes, int n_in,
                              void* d_out, int out_size, void* d_ws, size_t ws_size,
                              hipStream_t stream) {
    const float* F  = (const float*)d_in[0];   // (2048,128)
    const float* Wm = (const float*)d_in[1];   // (1000,128)
    float* out = (float*)d_out;                // (2048,1000)
    float* ws  = (float*)d_ws;

    proto_kernel<<<NPB, 256, 0, stream>>>(Wm, ws);                 // 136 partials
    dist_kernel <<<dim3(16, 16), 256, 0, stream>>>(F, Wm, ws, out);
}

// Round 8
// 66.616 us; speedup vs baseline: 1.3710x; 1.0869x over previous
//
#include <hip/hip_runtime.h>
#include <hip/hip_bf16.h>
#include <math.h>

#define NB   2048
#define NC   1000
#define DDIM 128
#define LDT  136      // LDS row stride in bf16 (+8 pad; 272 B rows keep 16B align)
#define NPB  136      // compact triangular proto blocks (by<=bx<16)

typedef __attribute__((ext_vector_type(8))) short  short8;
typedef __attribute__((ext_vector_type(4))) float  floatx4;

__device__ __forceinline__ float bf2f(unsigned short b) {
    union { float f; unsigned int u; } v; v.u = ((unsigned int)b) << 16;
    return v.f;
}

// stage 64 rows x 128 k of fp32 -> bf16 LDS tile (RNE), coalesced float4 reads
__device__ __forceinline__ void stage_cvt(const float* __restrict__ src, int row0, int clampr,
                                          unsigned short* __restrict__ lds, int t) {
    #pragma unroll
    for (int i = 0; i < 8; ++i) {
        int c = (i * 256 + t) * 4;
        int r = c >> 7, k = c & 127;
        int gr = row0 + r; if (gr > clampr) gr = clampr;
        float4 v = *(const float4*)(src + gr * DDIM + k);
        union { __hip_bfloat162 h; unsigned int u; } p0, p1;
        p0.h = __float22bfloat162_rn(make_float2(v.x, v.y));
        p1.h = __float22bfloat162_rn(make_float2(v.z, v.w));
        uint2 st; st.x = p0.u; st.y = p1.u;
        *(uint2*)(lds + r * LDT + k) = st;
    }
}

// per-row squared norms of the ROUNDED bf16 values; 4 lanes per row
__device__ __forceinline__ void norm64(const unsigned short* __restrict__ tile,
                                       float* __restrict__ nrm, int t) {
    int r = t >> 2, seg = t & 3;
    const unsigned short* p = tile + r * LDT + seg * 32;
    float q = 0.0f;
    #pragma unroll
    for (int j = 0; j < 4; ++j) {
        short8 v = *(const short8*)(p + j * 8);
        #pragma unroll
        for (int e = 0; e < 8; ++e) { float f = bf2f((unsigned short)v[e]); q = fmaf(f, f, q); }
    }
    q += __shfl_xor(q, 1);
    q += __shfl_xor(q, 2);
    if (seg == 0) nrm[r] = q;
}

// ---- proto: compact upper-triangle 64x64 tiles, partial -> ws[bid] ---------------
__global__ __launch_bounds__(256) void proto_kernel(const float* __restrict__ W,
                                                    float* __restrict__ ws) {
    __shared__ __align__(16) unsigned short As[64 * LDT];
    __shared__ __align__(16) unsigned short Bs[64 * LDT];
    __shared__ float nA[64], nB[64], red[4];
    int bid = blockIdx.x;
    int by = 0, base = 0;                      // map bid -> (by<=bx<16)
    while (base + (16 - by) <= bid) { base += 16 - by; ++by; }
    int bx = by + (bid - base);
    int t = threadIdx.x;
    int row0 = by * 64, col0 = bx * 64;
    stage_cvt(W, row0, NC - 1, As, t);
    stage_cvt(W, col0, NC - 1, Bs, t);
    __syncthreads();
    norm64(As, nA, t);
    norm64(Bs, nB, t);
    int lane = t & 63, w = t >> 6;
    int wm = (w >> 1) * 32, wn = (w & 1) * 32;
    int lm = lane & 15, q = lane >> 4;
    floatx4 acc[2][2] = {{{0,0,0,0},{0,0,0,0}},{{0,0,0,0},{0,0,0,0}}};
    #pragma unroll
    for (int ks = 0; ks < 4; ++ks) {
        int ko = ks * 32 + q * 8;
        short8 a0 = *(const short8*)(As + (wm + lm) * LDT + ko);
        short8 a1 = *(const short8*)(As + (wm + 16 + lm) * LDT + ko);
        short8 b0 = *(const short8*)(Bs + (wn + lm) * LDT + ko);
        short8 b1 = *(const short8*)(Bs + (wn + 16 + lm) * LDT + ko);
        acc[0][0] = __builtin_amdgcn_mfma_f32_16x16x32_bf16(a0, b0, acc[0][0], 0, 0, 0);
        acc[0][1] = __builtin_amdgcn_mfma_f32_16x16x32_bf16(a0, b1, acc[0][1], 0, 0, 0);
        acc[1][0] = __builtin_amdgcn_mfma_f32_16x16x32_bf16(a1, b0, acc[1][0], 0, 0, 0);
        acc[1][1] = __builtin_amdgcn_mfma_f32_16x16x32_bf16(a1, b1, acc[1][1], 0, 0, 0);
    }
    __syncthreads();                           // norms visible
    float local = 0.0f;
    #pragma unroll
    for (int ti = 0; ti < 2; ++ti)
        #pragma unroll
        for (int tj = 0; tj < 2; ++tj) {
            int lc2 = wn + tj * 16 + lm;
            if (col0 + lc2 < NC) {
                float n2 = nB[lc2];
                #pragma unroll
                for (int r = 0; r < 4; ++r) {
                    int lc1 = wm + ti * 16 + q * 4 + r;
                    if (row0 + lc1 < NC) {
                        float d2 = nA[lc1] + n2 - 2.0f * acc[ti][tj][r];
                        local += sqrtf(fmaxf(d2, 0.0f));
                    }
                }
            }
        }
    if (by != bx) local *= 2.0f;               // symmetric double-count
    #pragma unroll
    for (int off = 32; off > 0; off >>= 1) local += __shfl_down(local, off);
    if (lane == 0) red[w] = local;
    __syncthreads();
    if (t == 0) ws[bid] = red[0] + red[1] + red[2] + red[3];
}

// ---- dist: 64x64 tiles, swapped operands (m=c, n=b) for float4 stores ------------
__global__ __launch_bounds__(256) void dist_kernel(const float* __restrict__ F,
                                                   const float* __restrict__ W,
                                                   const float* __restrict__ ws,
                                                   float* __restrict__ out) {
    __shared__ __align__(16) unsigned short Fs[64 * LDT];
    __shared__ __align__(16) unsigned short Ws[64 * LDT];
    __shared__ float nF[64], nW[64], red2[4];
    int t = threadIdx.x;
    int row0 = blockIdx.y * 64, col0 = blockIdx.x * 64;   // row0: F rows, col0: W rows

    float pv = (t < NPB) ? ws[t] : 0.0f;       // proto partials (coalesced 544 B)
    stage_cvt(F, row0, NB - 1, Fs, t);
    stage_cvt(W, col0, NC - 1, Ws, t);
    #pragma unroll
    for (int off = 32; off > 0; off >>= 1) pv += __shfl_down(pv, off);
    if ((t & 63) == 0) red2[t >> 6] = pv;
    __syncthreads();                           // staging + red2 visible
    float proto = red2[0] + red2[1] + red2[2] + red2[3];

    norm64(Fs, nF, t);
    norm64(Ws, nW, t);
    int lane = t & 63, w = t >> 6;
    int wc = (w >> 1) * 32, wb = (w & 1) * 32; // wave offsets: c (m-dim), b (n-dim)
    int lm = lane & 15, q = lane >> 4;
    // A-frag from W tile (m=c), B-frag from F tile (n=b):
    //   D col = lane&15 -> b_local, D row = q*4+reg -> c_local (4 consecutive c/lane)
    floatx4 acc[2][2] = {{{0,0,0,0},{0,0,0,0}},{{0,0,0,0},{0,0,0,0}}};
    #pragma unroll
    for (int ks = 0; ks < 4; ++ks) {
        int ko = ks * 32 + q * 8;
        short8 a0 = *(const short8*)(Ws + (wc + lm) * LDT + ko);
        short8 a1 = *(const short8*)(Ws + (wc + 16 + lm) * LDT + ko);
        short8 b0 = *(const short8*)(Fs + (wb + lm) * LDT + ko);
        short8 b1 = *(const short8*)(Fs + (wb + 16 + lm) * LDT + ko);
        acc[0][0] = __builtin_amdgcn_mfma_f32_16x16x32_bf16(a0, b0, acc[0][0], 0, 0, 0);
        acc[0][1] = __builtin_amdgcn_mfma_f32_16x16x32_bf16(a0, b1, acc[0][1], 0, 0, 0);
        acc[1][0] = __builtin_amdgcn_mfma_f32_16x16x32_bf16(a1, b0, acc[1][0], 0, 0, 0);
        acc[1][1] = __builtin_amdgcn_mfma_f32_16x16x32_bf16(a1, b1, acc[1][1], 0, 0, 0);
    }
    __syncthreads();                           // norms visible
    #pragma unroll
    for (int ci = 0; ci < 2; ++ci) {
        int lcb = wc + ci * 16 + q * 4;        // c_local base for this lane
        int cb  = col0 + lcb;                  // global c base (quad-aligned)
        if (cb < NC) {                         // NC%4==0: quad all-or-nothing
            float nw0 = nW[lcb], nw1 = nW[lcb + 1], nw2 = nW[lcb + 2], nw3 = nW[lcb + 3];
            #pragma unroll
            for (int bj = 0; bj < 2; ++bj) {
                int lb = wb + bj * 16 + lm;
                int bg = row0 + lb;            // global F row
                float nb_ = nF[lb];
                floatx4 d = acc[ci][bj];
                float4 o;
                o.x = proto - sqrtf(fmaxf(nw0 + nb_ - 2.0f * d[0], 0.0f));
                o.y = proto - sqrtf(fmaxf(nw1 + nb_ - 2.0f * d[1], 0.0f));
                o.z = proto - sqrtf(fmaxf(nw2 + nb_ - 2.0f * d[2], 0.0f));
                o.w = proto - sqrtf(fmaxf(nw3 + nb_ - 2.0f * d[3], 0.0f));
                *(float4*)(out + bg * NC + cb) = o;
            }
        }
    }
}

extern "C" void kernel_launch(void* const* d_in, const int* in_sizes, int n_in,
                              void* d_out, int out_size, void* d_ws, size_t ws_size,
                              hipStream_t stream) {
    const float* F  = (const float*)d_in[0];   // (2048,128)
    const float* Wm = (const float*)d_in[1];   // (1000,128)
    float* out = (float*)d_out;                // (2048,1000)
    float* ws  = (float*)d_ws;

    proto_kernel<<<NPB, 256, 0, stream>>>(Wm, ws);                  // 136 partials
    dist_kernel <<<dim3(16, 32), 256, 0, stream>>>(F, Wm, ws, out); // 512 tiles
}